// Round 10
// baseline (189.665 us; speedup 1.0000x reference)
//
#include <hip/hip_runtime.h>

typedef __attribute__((ext_vector_type(8))) __bf16 bf16x8;
typedef __attribute__((ext_vector_type(8))) unsigned short u16x8;
typedef __attribute__((ext_vector_type(4))) float f32x4;

#define LOG2E 1.4426950408889634f

__device__ __forceinline__ unsigned short f2b(float f) {
  unsigned u = __float_as_uint(f);
  u += 0x7fffu + ((u >> 16) & 1u);   // RNE
  return (unsigned short)(u >> 16);
}
__device__ __forceinline__ float b2f(unsigned short h) {
  return __uint_as_float(((unsigned)h) << 16);
}

// ---------------- 1) x fp32 -> bf16 (row-major [4096][1024]) ----------------
__global__ __launch_bounds__(256) void k_cvt_x(const float* __restrict__ in,
                                               unsigned short* __restrict__ out, int n4) {
  int i = blockIdx.x * blockDim.x + threadIdx.x;
  if (i >= n4) return;
  float4 f = ((const float4*)in)[i];
  ushort4 o;
  o.x = f2b(f.x); o.y = f2b(f.y); o.z = f2b(f.z); o.w = f2b(f.w);
  ((ushort4*)out)[i] = o;
}

// ------- 2) W [1024][2048] fp32 -> Wt [2048][1024] bf16 (transposed) --------
__global__ __launch_bounds__(256) void k_trans_w(const float* __restrict__ W,
                                                 unsigned short* __restrict__ Wt) {
  __shared__ unsigned short tile[64][65];
  int n0 = blockIdx.x * 64;
  int k0 = blockIdx.y * 64;
  int tx = threadIdx.x & 63, ty = threadIdx.x >> 6;
#pragma unroll
  for (int r = 0; r < 16; ++r) {
    int kk = ty * 16 + r;
    tile[kk][tx] = f2b(W[(size_t)(k0 + kk) * 2048 + n0 + tx]);
  }
  __syncthreads();
#pragma unroll
  for (int r = 0; r < 16; ++r) {
    int nn = ty * 16 + r;
    Wt[(size_t)(n0 + nn) * 1024 + k0 + tx] = tile[tx][nn];
  }
}

// ---- 3) GEMM: qk[4096][2048] bf16 = xb[4096][1024] @ Wt[2048][1024]^T ------
__global__ __launch_bounds__(256) void k_gemm_qk(const unsigned short* __restrict__ A,
                                                 const unsigned short* __restrict__ Bt,
                                                 unsigned short* __restrict__ C) {
  __shared__ unsigned short As[128 * 32];
  __shared__ unsigned short Bs[128 * 32];
  const int K = 1024;
  int m0 = blockIdx.x * 128;
  int n0 = blockIdx.y * 128;
  int tid = threadIdx.x;
  int w = tid >> 6, lane = tid & 63;
  int lq = lane & 15, lk8 = (lane >> 4) * 8;
  int wr = (w >> 1) * 64, wc = (w & 1) * 64;
  f32x4 acc[4][4];
#pragma unroll
  for (int i = 0; i < 4; ++i)
#pragma unroll
    for (int j = 0; j < 4; ++j)
#pragma unroll
      for (int r = 0; r < 4; ++r) acc[i][j][r] = 0.f;

  for (int kk = 0; kk < K; kk += 32) {
    bf16x8 sa[2], sb[2];
#pragma unroll
    for (int i = 0; i < 2; ++i) {
      int c = tid + 256 * i;
      int row = c >> 2, col = (c & 3) * 8;
      sa[i] = *(const bf16x8*)(A + (size_t)(m0 + row) * K + kk + col);
      sb[i] = *(const bf16x8*)(Bt + (size_t)(n0 + row) * K + kk + col);
    }
    __syncthreads();
#pragma unroll
    for (int i = 0; i < 2; ++i) {
      int c = tid + 256 * i;
      int row = c >> 2, col = (c & 3) * 8;
      *(bf16x8*)(As + row * 32 + col) = sa[i];
      *(bf16x8*)(Bs + row * 32 + col) = sb[i];
    }
    __syncthreads();
    bf16x8 af[4], bf[4];
#pragma unroll
    for (int i = 0; i < 4; ++i) af[i] = *(const bf16x8*)(As + (wr + i * 16 + lq) * 32 + lk8);
#pragma unroll
    for (int j = 0; j < 4; ++j) bf[j] = *(const bf16x8*)(Bs + (wc + j * 16 + lq) * 32 + lk8);
#pragma unroll
    for (int i = 0; i < 4; ++i)
#pragma unroll
      for (int j = 0; j < 4; ++j)
        acc[i][j] = __builtin_amdgcn_mfma_f32_16x16x32_bf16(af[i], bf[j], acc[i][j], 0, 0, 0);
  }
#pragma unroll
  for (int i = 0; i < 4; ++i)
#pragma unroll
    for (int j = 0; j < 4; ++j)
#pragma unroll
      for (int r = 0; r < 4; ++r) {
        int m = m0 + wr + i * 16 + (lane >> 4) * 4 + r;
        int n = n0 + wc + j * 16 + lq;
        C[(size_t)m * 2048 + n] = f2b(acc[i][j][r]);
      }
}

// ------- 4) v[b,t,j,d] = sum_i x[b,t,i*64+d] * v_tmp[i*16+j]  (bf16) --------
__global__ __launch_bounds__(256) void k_vcomp(const float* __restrict__ x,
                                               const float* __restrict__ vt,
                                               unsigned short* __restrict__ vb) {
  __shared__ float s_vt[256];
  s_vt[threadIdx.x] = vt[threadIdx.x];
  __syncthreads();
  int g = blockIdx.x * 256 + threadIdx.x;
  int bt = g >> 6, d = g & 63;
  const float* xp = x + (size_t)bt * 1024 + d;
  float xi[16];
#pragma unroll
  for (int i = 0; i < 16; ++i) xi[i] = xp[i * 64];
#pragma unroll
  for (int j = 0; j < 16; ++j) {
    float s = 0.f;
#pragma unroll
    for (int i = 0; i < 16; ++i) s += xi[i] * s_vt[i * 16 + j];
    vb[(size_t)bt * 1024 + j * 64 + d] = f2b(s);
  }
}

// ------- 5) vb [2][2048][1024] -> Vt [2][1024][2048]  (t-major for PV) ------
__global__ __launch_bounds__(256) void k_vtrans(const unsigned short* __restrict__ vb,
                                                unsigned short* __restrict__ Vt) {
  __shared__ unsigned short tile[64][65];
  int t0 = blockIdx.x * 64;
  int c0 = blockIdx.y * 64;
  int b = blockIdx.z;
  int tx = threadIdx.x & 63, ty = threadIdx.x >> 6;
#pragma unroll
  for (int r = 0; r < 16; ++r) {
    int tt = ty * 16 + r;
    tile[tt][tx] = vb[((size_t)b * 2048 + t0 + tt) * 1024 + c0 + tx];
  }
  __syncthreads();
#pragma unroll
  for (int r = 0; r < 16; ++r) {
    int cc = ty * 16 + r;
    Vt[((size_t)b * 1024 + c0 + cc) * 2048 + t0 + tx] = tile[tx][cc];
  }
}

// ---------------- 6) causal flash attention with ALiBi ----------------------
// R10: (a) XOR-swizzled Ks/Vs chunk layout — 16B chunk c of row r stored at
// c^((r>>1)&3): fragment ds_read_b128 start banks become 2-way (free) instead
// of 8-way (2.9x). (b) grid 1024 blocks (4/CU, 50% occ cap): one q-tile per
// block, balance remap qt = ((h>>2)&1) ? 31-bx : bx (round-robin gives each
// CU {t,31-t,t,31-t} = 66 tiles). Keeps: LDS staging dbuf (m97 pattern),
// fixed-shift softmax, ones-column l, swizzled Pbuf, u16 LDS typing (TBAA).
__global__ __launch_bounds__(256) void k_flash(const unsigned short* __restrict__ qkb, // [2][2048][2048]
                                               const unsigned short* __restrict__ Vt,  // [2][1024][2048]
                                               unsigned short* __restrict__ y) {       // [2][2048][1024]
  __shared__ unsigned short Ks[2][2][64 * 32];   // [buf][half][row][chunk-swizzled]
  __shared__ unsigned short Vs[2][2][64 * 32];
  __shared__ unsigned short Pbuf[4][16 * 64];
  int hd = blockIdx.y, b = blockIdx.z;
  int tid = threadIdx.x;
  int w = tid >> 6, lane = tid & 63;
  int quad = lane >> 4, lq = lane & 15, lk8 = quad * 8;
  int rs = tid >> 2;                               // staging row
  int scc = (((tid & 3) ^ ((rs >> 1) & 3)) * 8);   // staging chunk (swizzled)
  int rcc = ((quad ^ ((lq >> 1) & 3)) * 8);        // fragment chunk (swizzled)
  const size_t rowb = (size_t)b * 2048;
  const size_t vrow = ((size_t)b * 1024 + hd * 64 + rs) * 2048 + (tid & 3) * 8;
  const size_t krow = ((rowb + rs) << 11) + 1024 + hd * 64 + (tid & 3) * 8;

  float slope = exp2f(-0.5f * (float)(hd + 1));  // ALiBi, H=16 power-of-2
  const float c1 = 0.125f * LOG2E;               // 1/sqrt(64) * log2(e)
  const float c2 = slope * LOG2E;
  const float SHIFT = 16.0f;                     // fixed softmax shift (log2)

  bf16x8 ones;
#pragma unroll
  for (int i = 0; i < 8; ++i) ones[i] = (__bf16)1.0f;

  // balance remap: per-CU round-robin gets {t, 31-t, t, 31-t}
  int qt = ((hd >> 2) & 1) ? (31 - (int)blockIdx.x) : (int)blockIdx.x;
  int q0 = qt * 64;
  int qg = q0 + w * 16 + lq;                     // A-frag row (m = lane&15)

  bf16x8 qf0 = *(const bf16x8*)(qkb + ((rowb + qg) << 11) + hd * 64 + lk8);
  bf16x8 qf1 = *(const bf16x8*)(qkb + ((rowb + qg) << 11) + hd * 64 + 32 + lk8);

  int qrow_base = q0 + w * 16 + quad * 4;        // C-layout rows: + r

  f32x4 o[4], o4;
#pragma unroll
  for (int r = 0; r < 4; ++r) o4[r] = 0.f;
#pragma unroll
  for (int j = 0; j < 4; ++j)
#pragma unroll
    for (int r = 0; r < 4; ++r) o[j][r] = 0.f;

  // ---- prologue: stage tile 0 into buffer 0 ----
  {
    u16x8 pk0 = *(const u16x8*)(qkb + krow);
    u16x8 pk1 = *(const u16x8*)(qkb + krow + 32);
    u16x8 pv0 = *(const u16x8*)(Vt + vrow);
    u16x8 pv1 = *(const u16x8*)(Vt + vrow + 32);
    *(u16x8*)(&Ks[0][0][rs * 32 + scc]) = pk0;
    *(u16x8*)(&Ks[0][1][rs * 32 + scc]) = pk1;
    *(u16x8*)(&Vs[0][0][rs * 32 + scc]) = pv0;
    *(u16x8*)(&Vs[0][1][rs * 32 + scc]) = pv1;
    __syncthreads();
  }
  int cur = 0;

#pragma unroll 1
  for (int kt = 0; kt <= qt; ++kt) {
    int k0 = kt * 64;
    // prefetch tile kt+1 into registers (issued first, consumed at tile end)
    u16x8 pk0, pk1, pv0, pv1;
    if (kt < qt) {
      size_t koff = (size_t)(k0 + 64);
      pk0 = *(const u16x8*)(qkb + krow + (koff << 11));
      pk1 = *(const u16x8*)(qkb + krow + (koff << 11) + 32);
      pv0 = *(const u16x8*)(Vt + vrow + koff);
      pv1 = *(const u16x8*)(Vt + vrow + koff + 32);
    }
    // K fragments from LDS (swizzled chunk -> conflict-free)
    bf16x8 kc[4][2];
#pragma unroll
    for (int s4 = 0; s4 < 4; ++s4) {
      u16x8 t0 = *(const u16x8*)(&Ks[cur][0][(s4 * 16 + lq) * 32 + rcc]);
      u16x8 t1 = *(const u16x8*)(&Ks[cur][1][(s4 * 16 + lq) * 32 + rcc]);
      kc[s4][0] = __builtin_bit_cast(bf16x8, t0);
      kc[s4][1] = __builtin_bit_cast(bf16x8, t1);
    }
    // QK^T
    f32x4 S[4];
#pragma unroll
    for (int s4 = 0; s4 < 4; ++s4) {
      f32x4 a;
#pragma unroll
      for (int r = 0; r < 4; ++r) a[r] = 0.f;
      a = __builtin_amdgcn_mfma_f32_16x16x32_bf16(qf0, kc[s4][0], a, 0, 0, 0);
      a = __builtin_amdgcn_mfma_f32_16x16x32_bf16(qf1, kc[s4][1], a, 0, 0, 0);
      S[s4] = a;
    }
    // p = exp2(score - SHIFT); masked cols -> 0
    float p[4][4];
    if (kt == qt) {
#pragma unroll
      for (int s4 = 0; s4 < 4; ++s4) {
        int kg = k0 + s4 * 16 + lq;
#pragma unroll
        for (int r = 0; r < 4; ++r) {
          int qr = qrow_base + r;
          float v = S[s4][r] * c1 + (c2 * (float)(kg - qr) - SHIFT);
          v = (kg <= qr) ? v : -1e30f;
          p[s4][r] = exp2f(v);
        }
      }
    } else {
#pragma unroll
      for (int s4 = 0; s4 < 4; ++s4) {
        int kg = k0 + s4 * 16 + lq;
#pragma unroll
        for (int r = 0; r < 4; ++r) {
          int qr = qrow_base + r;
          float v = S[s4][r] * c1 + (c2 * (float)(kg - qr) - SHIFT);
          p[s4][r] = exp2f(v);
        }
      }
    }
    // P: C-layout -> LDS (XOR-swizzled) -> A-layout (per-wave, no barrier)
#pragma unroll
    for (int s4 = 0; s4 < 4; ++s4) {
      int cg = (s4 ^ quad) << 4;
#pragma unroll
      for (int r = 0; r < 4; ++r)
        Pbuf[w][(quad * 4 + r) * 64 + cg + lq] = f2b(p[s4][r]);
    }
    int g0 = ((quad >> 1) ^ (lq >> 2)) << 4;
    int g1 = ((2 | (quad >> 1)) ^ (lq >> 2)) << 4;
    int sub = (quad & 1) * 8;
    u16x8 t0 = *(const u16x8*)(&Pbuf[w][lq * 64 + g0 + sub]);
    u16x8 t1 = *(const u16x8*)(&Pbuf[w][lq * 64 + g1 + sub]);
    bf16x8 pf0 = __builtin_bit_cast(bf16x8, t0);
    bf16x8 pf1 = __builtin_bit_cast(bf16x8, t1);
    // V fragments from LDS (swizzled), then PV + ones-column
#pragma unroll
    for (int j = 0; j < 4; ++j) {
      u16x8 v0 = *(const u16x8*)(&Vs[cur][0][(j * 16 + lq) * 32 + rcc]);
      u16x8 v1 = *(const u16x8*)(&Vs[cur][1][(j * 16 + lq) * 32 + rcc]);
      bf16x8 vf0 = __builtin_bit_cast(bf16x8, v0);
      bf16x8 vf1 = __builtin_bit_cast(bf16x8, v1);
      o[j] = __builtin_amdgcn_mfma_f32_16x16x32_bf16(pf0, vf0, o[j], 0, 0, 0);
      o[j] = __builtin_amdgcn_mfma_f32_16x16x32_bf16(pf1, vf1, o[j], 0, 0, 0);
      if (j == 0) {
        o4 = __builtin_amdgcn_mfma_f32_16x16x32_bf16(pf0, ones, o4, 0, 0, 0);
        o4 = __builtin_amdgcn_mfma_f32_16x16x32_bf16(pf1, ones, o4, 0, 0, 0);
      }
    }
    // stage prefetched tile into the other buffer; single barrier per tile
    if (kt < qt) {
      int nxt = cur ^ 1;
      *(u16x8*)(&Ks[nxt][0][rs * 32 + scc]) = pk0;
      *(u16x8*)(&Ks[nxt][1][rs * 32 + scc]) = pk1;
      *(u16x8*)(&Vs[nxt][0][rs * 32 + scc]) = pv0;
      *(u16x8*)(&Vs[nxt][1][rs * 32 + scc]) = pv1;
      __syncthreads();
      cur = nxt;
    }
  }
#pragma unroll
  for (int r = 0; r < 4; ++r) {
    float inv = 1.0f / o4[r];     // l (all cols of ones-acc equal)
    int qr = qrow_base + r;
#pragma unroll
    for (int j = 0; j < 4; ++j)
      y[((rowb + qr) << 10) + hd * 64 + j * 16 + lq] = f2b(o[j][r] * inv);
  }
}

// --- 7) out[b,t,i*64+d] = sum_j y[b,t,j*64+d] * proj_tmp[i*16+j]  (FP32 out) ---
__global__ __launch_bounds__(256) void k_proj(const unsigned short* __restrict__ yb,
                                              const float* __restrict__ pt,
                                              float* __restrict__ out) {
  __shared__ float s_pt[256];
  s_pt[threadIdx.x] = pt[threadIdx.x];
  __syncthreads();
  int g = blockIdx.x * 256 + threadIdx.x;
  int bt = g >> 6, d = g & 63;
  float yj[16];
#pragma unroll
  for (int j = 0; j < 16; ++j) yj[j] = b2f(yb[(size_t)bt * 1024 + j * 64 + d]);
#pragma unroll
  for (int i = 0; i < 16; ++i) {
    float s = 0.f;
#pragma unroll
    for (int j = 0; j < 16; ++j) s += yj[j] * s_pt[i * 16 + j];
    out[(size_t)bt * 1024 + i * 64 + d] = s;
  }
}

extern "C" void kernel_launch(void* const* d_in, const int* in_sizes, int n_in,
                              void* d_out, int out_size, void* d_ws, size_t ws_size,
                              hipStream_t stream) {
  const float* x  = (const float*)d_in[0];   // [2][2048][1024] fp32
  const float* W  = (const float*)d_in[1];   // [1024][2048] fp32
  const float* vt = (const float*)d_in[2];   // [16][16] fp32
  const float* pt = (const float*)d_in[3];   // [16][16] fp32
  float* out = (float*)d_out;                // fp32 out

  char* ws = (char*)d_ws;
  unsigned short* xb  = (unsigned short*)(ws);                 //  8 MiB, reused as y
  unsigned short* Wt  = (unsigned short*)(ws + (8u  << 20));   //  4 MiB
  unsigned short* qkb = (unsigned short*)(ws + (12u << 20));   // 16 MiB
  unsigned short* vb  = (unsigned short*)(ws + (28u << 20));   //  8 MiB
  unsigned short* Vtr = (unsigned short*)(ws + (36u << 20));   //  8 MiB
  unsigned short* yb  = xb;  // xb dead after GEMM; flash writes y there

  k_cvt_x  <<<4096, 256, 0, stream>>>(x, xb, 4194304 / 4);
  k_trans_w<<<dim3(32, 16), 256, 0, stream>>>(W, Wt);
  k_gemm_qk<<<dim3(32, 16), 256, 0, stream>>>(xb, Wt, qkb);
  k_vcomp  <<<1024, 256, 0, stream>>>(x, vt, vb);
  k_vtrans <<<dim3(32, 16, 2), 256, 0, stream>>>(vb, Vtr);
  k_flash  <<<dim3(32, 16, 2), 256, 0, stream>>>(qkb, Vtr, yb);
  k_proj   <<<1024, 256, 0, stream>>>(yb, pt, out);
}

// Round 11
// 189.344 us; speedup vs baseline: 1.0017x; 1.0017x over previous
//
#include <hip/hip_runtime.h>

typedef __attribute__((ext_vector_type(8))) __bf16 bf16x8;
typedef __attribute__((ext_vector_type(8))) unsigned short u16x8;
typedef __attribute__((ext_vector_type(4))) float f32x4;

#define LOG2E 1.4426950408889634f

__device__ __forceinline__ unsigned short f2b(float f) {
  unsigned u = __float_as_uint(f);
  u += 0x7fffu + ((u >> 16) & 1u);   // RNE
  return (unsigned short)(u >> 16);
}
__device__ __forceinline__ float b2f(unsigned short h) {
  return __uint_as_float(((unsigned)h) << 16);
}

// ---------------- 1) x fp32 -> bf16 (row-major [4096][1024]) ----------------
__global__ __launch_bounds__(256) void k_cvt_x(const float* __restrict__ in,
                                               unsigned short* __restrict__ out, int n4) {
  int i = blockIdx.x * blockDim.x + threadIdx.x;
  if (i >= n4) return;
  float4 f = ((const float4*)in)[i];
  ushort4 o;
  o.x = f2b(f.x); o.y = f2b(f.y); o.z = f2b(f.z); o.w = f2b(f.w);
  ((ushort4*)out)[i] = o;
}

// ------- 2) W [1024][2048] fp32 -> Wt [2048][1024] bf16 (transposed) --------
__global__ __launch_bounds__(256) void k_trans_w(const float* __restrict__ W,
                                                 unsigned short* __restrict__ Wt) {
  __shared__ unsigned short tile[64][65];
  int n0 = blockIdx.x * 64;
  int k0 = blockIdx.y * 64;
  int tx = threadIdx.x & 63, ty = threadIdx.x >> 6;
#pragma unroll
  for (int r = 0; r < 16; ++r) {
    int kk = ty * 16 + r;
    tile[kk][tx] = f2b(W[(size_t)(k0 + kk) * 2048 + n0 + tx]);
  }
  __syncthreads();
#pragma unroll
  for (int r = 0; r < 16; ++r) {
    int nn = ty * 16 + r;
    Wt[(size_t)(n0 + nn) * 1024 + k0 + tx] = tile[tx][nn];
  }
}

// ---- 3) GEMM: qk[4096][2048] bf16 = xb[4096][1024] @ Wt[2048][1024]^T ------
__global__ __launch_bounds__(256) void k_gemm_qk(const unsigned short* __restrict__ A,
                                                 const unsigned short* __restrict__ Bt,
                                                 unsigned short* __restrict__ C) {
  __shared__ unsigned short As[128 * 32];
  __shared__ unsigned short Bs[128 * 32];
  const int K = 1024;
  int m0 = blockIdx.x * 128;
  int n0 = blockIdx.y * 128;
  int tid = threadIdx.x;
  int w = tid >> 6, lane = tid & 63;
  int lq = lane & 15, lk8 = (lane >> 4) * 8;
  int wr = (w >> 1) * 64, wc = (w & 1) * 64;
  f32x4 acc[4][4];
#pragma unroll
  for (int i = 0; i < 4; ++i)
#pragma unroll
    for (int j = 0; j < 4; ++j)
#pragma unroll
      for (int r = 0; r < 4; ++r) acc[i][j][r] = 0.f;

  for (int kk = 0; kk < K; kk += 32) {
    bf16x8 sa[2], sb[2];
#pragma unroll
    for (int i = 0; i < 2; ++i) {
      int c = tid + 256 * i;
      int row = c >> 2, col = (c & 3) * 8;
      sa[i] = *(const bf16x8*)(A + (size_t)(m0 + row) * K + kk + col);
      sb[i] = *(const bf16x8*)(Bt + (size_t)(n0 + row) * K + kk + col);
    }
    __syncthreads();
#pragma unroll
    for (int i = 0; i < 2; ++i) {
      int c = tid + 256 * i;
      int row = c >> 2, col = (c & 3) * 8;
      *(bf16x8*)(As + row * 32 + col) = sa[i];
      *(bf16x8*)(Bs + row * 32 + col) = sb[i];
    }
    __syncthreads();
    bf16x8 af[4], bf[4];
#pragma unroll
    for (int i = 0; i < 4; ++i) af[i] = *(const bf16x8*)(As + (wr + i * 16 + lq) * 32 + lk8);
#pragma unroll
    for (int j = 0; j < 4; ++j) bf[j] = *(const bf16x8*)(Bs + (wc + j * 16 + lq) * 32 + lk8);
#pragma unroll
    for (int i = 0; i < 4; ++i)
#pragma unroll
      for (int j = 0; j < 4; ++j)
        acc[i][j] = __builtin_amdgcn_mfma_f32_16x16x32_bf16(af[i], bf[j], acc[i][j], 0, 0, 0);
  }
#pragma unroll
  for (int i = 0; i < 4; ++i)
#pragma unroll
    for (int j = 0; j < 4; ++j)
#pragma unroll
      for (int r = 0; r < 4; ++r) {
        int m = m0 + wr + i * 16 + (lane >> 4) * 4 + r;
        int n = n0 + wc + j * 16 + lq;
        C[(size_t)m * 2048 + n] = f2b(acc[i][j][r]);
      }
}

// ------- 4) v[b,t,j,d] = sum_i x[b,t,i*64+d] * v_tmp[i*16+j]  (bf16) --------
__global__ __launch_bounds__(256) void k_vcomp(const float* __restrict__ x,
                                               const float* __restrict__ vt,
                                               unsigned short* __restrict__ vb) {
  __shared__ float s_vt[256];
  s_vt[threadIdx.x] = vt[threadIdx.x];
  __syncthreads();
  int g = blockIdx.x * 256 + threadIdx.x;
  int bt = g >> 6, d = g & 63;
  const float* xp = x + (size_t)bt * 1024 + d;
  float xi[16];
#pragma unroll
  for (int i = 0; i < 16; ++i) xi[i] = xp[i * 64];
#pragma unroll
  for (int j = 0; j < 16; ++j) {
    float s = 0.f;
#pragma unroll
    for (int i = 0; i < 16; ++i) s += xi[i] * s_vt[i * 16 + j];
    vb[(size_t)bt * 1024 + j * 64 + d] = f2b(s);
  }
}

// ------- 5) vb [2][2048][1024] -> Vt [2][1024][2048]  (t-major for PV) ------
__global__ __launch_bounds__(256) void k_vtrans(const unsigned short* __restrict__ vb,
                                                unsigned short* __restrict__ Vt) {
  __shared__ unsigned short tile[64][65];
  int t0 = blockIdx.x * 64;
  int c0 = blockIdx.y * 64;
  int b = blockIdx.z;
  int tx = threadIdx.x & 63, ty = threadIdx.x >> 6;
#pragma unroll
  for (int r = 0; r < 16; ++r) {
    int tt = ty * 16 + r;
    tile[tt][tx] = vb[((size_t)b * 2048 + t0 + tt) * 1024 + c0 + tx];
  }
  __syncthreads();
#pragma unroll
  for (int r = 0; r < 16; ++r) {
    int cc = ty * 16 + r;
    Vt[((size_t)b * 1024 + c0 + cc) * 2048 + t0 + tx] = tile[tx][cc];
  }
}

// ---------------- 6) causal flash attention with ALiBi ----------------------
// R11: R10 with the balance remap bit CORRECTED. Round-robin places blocks
// c, c+256, c+512, c+768 on one CU; +256 linear = +8 in hd, so the remap bit
// must flip under hd+=8: use (hd>>3)&1 (R10's (hd>>2)&1 was invariant ->
// every CU got 4 same-qt blocks -> R3-style imbalance, 72 us). Per-CU now
// {t,31-t,t,31-t} = 66 tiles, 16 waves resident (4 x 40 KB LDS = 160 KB).
// Keeps: XOR-swizzled Ks/Vs (conflicts 4.87M->0.54M, verified R10), LDS
// staging dbuf, fixed-shift softmax, ones-column l, swizzled Pbuf, u16 typing.
__global__ __launch_bounds__(256) void k_flash(const unsigned short* __restrict__ qkb, // [2][2048][2048]
                                               const unsigned short* __restrict__ Vt,  // [2][1024][2048]
                                               unsigned short* __restrict__ y) {       // [2][2048][1024]
  __shared__ unsigned short Ks[2][2][64 * 32];   // [buf][half][row][chunk-swizzled]
  __shared__ unsigned short Vs[2][2][64 * 32];
  __shared__ unsigned short Pbuf[4][16 * 64];
  int hd = blockIdx.y, b = blockIdx.z;
  int tid = threadIdx.x;
  int w = tid >> 6, lane = tid & 63;
  int quad = lane >> 4, lq = lane & 15, lk8 = quad * 8;
  int rs = tid >> 2;                               // staging row
  int scc = (((tid & 3) ^ ((rs >> 1) & 3)) * 8);   // staging chunk (swizzled)
  int rcc = ((quad ^ ((lq >> 1) & 3)) * 8);        // fragment chunk (swizzled)
  const size_t rowb = (size_t)b * 2048;
  const size_t vrow = ((size_t)b * 1024 + hd * 64 + rs) * 2048 + (tid & 3) * 8;
  const size_t krow = ((rowb + rs) << 11) + 1024 + hd * 64 + (tid & 3) * 8;

  float slope = exp2f(-0.5f * (float)(hd + 1));  // ALiBi, H=16 power-of-2
  const float c1 = 0.125f * LOG2E;               // 1/sqrt(64) * log2(e)
  const float c2 = slope * LOG2E;
  const float SHIFT = 16.0f;                     // fixed softmax shift (log2)

  bf16x8 ones;
#pragma unroll
  for (int i = 0; i < 8; ++i) ones[i] = (__bf16)1.0f;

  // balance remap: +256 linear = +8 in hd -> (hd>>3)&1 flips per CU step
  int qt = ((hd >> 3) & 1) ? (31 - (int)blockIdx.x) : (int)blockIdx.x;
  int q0 = qt * 64;
  int qg = q0 + w * 16 + lq;                     // A-frag row (m = lane&15)

  bf16x8 qf0 = *(const bf16x8*)(qkb + ((rowb + qg) << 11) + hd * 64 + lk8);
  bf16x8 qf1 = *(const bf16x8*)(qkb + ((rowb + qg) << 11) + hd * 64 + 32 + lk8);

  int qrow_base = q0 + w * 16 + quad * 4;        // C-layout rows: + r

  f32x4 o[4], o4;
#pragma unroll
  for (int r = 0; r < 4; ++r) o4[r] = 0.f;
#pragma unroll
  for (int j = 0; j < 4; ++j)
#pragma unroll
    for (int r = 0; r < 4; ++r) o[j][r] = 0.f;

  // ---- prologue: stage tile 0 into buffer 0 ----
  {
    u16x8 pk0 = *(const u16x8*)(qkb + krow);
    u16x8 pk1 = *(const u16x8*)(qkb + krow + 32);
    u16x8 pv0 = *(const u16x8*)(Vt + vrow);
    u16x8 pv1 = *(const u16x8*)(Vt + vrow + 32);
    *(u16x8*)(&Ks[0][0][rs * 32 + scc]) = pk0;
    *(u16x8*)(&Ks[0][1][rs * 32 + scc]) = pk1;
    *(u16x8*)(&Vs[0][0][rs * 32 + scc]) = pv0;
    *(u16x8*)(&Vs[0][1][rs * 32 + scc]) = pv1;
    __syncthreads();
  }
  int cur = 0;

#pragma unroll 1
  for (int kt = 0; kt <= qt; ++kt) {
    int k0 = kt * 64;
    // prefetch tile kt+1 into registers (issued first, consumed at tile end)
    u16x8 pk0, pk1, pv0, pv1;
    if (kt < qt) {
      size_t koff = (size_t)(k0 + 64);
      pk0 = *(const u16x8*)(qkb + krow + (koff << 11));
      pk1 = *(const u16x8*)(qkb + krow + (koff << 11) + 32);
      pv0 = *(const u16x8*)(Vt + vrow + koff);
      pv1 = *(const u16x8*)(Vt + vrow + koff + 32);
    }
    // K fragments from LDS (swizzled chunk -> conflict-free)
    bf16x8 kc[4][2];
#pragma unroll
    for (int s4 = 0; s4 < 4; ++s4) {
      u16x8 t0 = *(const u16x8*)(&Ks[cur][0][(s4 * 16 + lq) * 32 + rcc]);
      u16x8 t1 = *(const u16x8*)(&Ks[cur][1][(s4 * 16 + lq) * 32 + rcc]);
      kc[s4][0] = __builtin_bit_cast(bf16x8, t0);
      kc[s4][1] = __builtin_bit_cast(bf16x8, t1);
    }
    // QK^T
    f32x4 S[4];
#pragma unroll
    for (int s4 = 0; s4 < 4; ++s4) {
      f32x4 a;
#pragma unroll
      for (int r = 0; r < 4; ++r) a[r] = 0.f;
      a = __builtin_amdgcn_mfma_f32_16x16x32_bf16(qf0, kc[s4][0], a, 0, 0, 0);
      a = __builtin_amdgcn_mfma_f32_16x16x32_bf16(qf1, kc[s4][1], a, 0, 0, 0);
      S[s4] = a;
    }
    // p = exp2(score - SHIFT); masked cols -> 0
    float p[4][4];
    if (kt == qt) {
#pragma unroll
      for (int s4 = 0; s4 < 4; ++s4) {
        int kg = k0 + s4 * 16 + lq;
#pragma unroll
        for (int r = 0; r < 4; ++r) {
          int qr = qrow_base + r;
          float v = S[s4][r] * c1 + (c2 * (float)(kg - qr) - SHIFT);
          v = (kg <= qr) ? v : -1e30f;
          p[s4][r] = exp2f(v);
        }
      }
    } else {
#pragma unroll
      for (int s4 = 0; s4 < 4; ++s4) {
        int kg = k0 + s4 * 16 + lq;
#pragma unroll
        for (int r = 0; r < 4; ++r) {
          int qr = qrow_base + r;
          float v = S[s4][r] * c1 + (c2 * (float)(kg - qr) - SHIFT);
          p[s4][r] = exp2f(v);
        }
      }
    }
    // P: C-layout -> LDS (XOR-swizzled) -> A-layout (per-wave, no barrier)
#pragma unroll
    for (int s4 = 0; s4 < 4; ++s4) {
      int cg = (s4 ^ quad) << 4;
#pragma unroll
      for (int r = 0; r < 4; ++r)
        Pbuf[w][(quad * 4 + r) * 64 + cg + lq] = f2b(p[s4][r]);
    }
    int g0 = ((quad >> 1) ^ (lq >> 2)) << 4;
    int g1 = ((2 | (quad >> 1)) ^ (lq >> 2)) << 4;
    int sub = (quad & 1) * 8;
    u16x8 t0 = *(const u16x8*)(&Pbuf[w][lq * 64 + g0 + sub]);
    u16x8 t1 = *(const u16x8*)(&Pbuf[w][lq * 64 + g1 + sub]);
    bf16x8 pf0 = __builtin_bit_cast(bf16x8, t0);
    bf16x8 pf1 = __builtin_bit_cast(bf16x8, t1);
    // V fragments from LDS (swizzled), then PV + ones-column
#pragma unroll
    for (int j = 0; j < 4; ++j) {
      u16x8 v0 = *(const u16x8*)(&Vs[cur][0][(j * 16 + lq) * 32 + rcc]);
      u16x8 v1 = *(const u16x8*)(&Vs[cur][1][(j * 16 + lq) * 32 + rcc]);
      bf16x8 vf0 = __builtin_bit_cast(bf16x8, v0);
      bf16x8 vf1 = __builtin_bit_cast(bf16x8, v1);
      o[j] = __builtin_amdgcn_mfma_f32_16x16x32_bf16(pf0, vf0, o[j], 0, 0, 0);
      o[j] = __builtin_amdgcn_mfma_f32_16x16x32_bf16(pf1, vf1, o[j], 0, 0, 0);
      if (j == 0) {
        o4 = __builtin_amdgcn_mfma_f32_16x16x32_bf16(pf0, ones, o4, 0, 0, 0);
        o4 = __builtin_amdgcn_mfma_f32_16x16x32_bf16(pf1, ones, o4, 0, 0, 0);
      }
    }
    // stage prefetched tile into the other buffer; single barrier per tile
    if (kt < qt) {
      int nxt = cur ^ 1;
      *(u16x8*)(&Ks[nxt][0][rs * 32 + scc]) = pk0;
      *(u16x8*)(&Ks[nxt][1][rs * 32 + scc]) = pk1;
      *(u16x8*)(&Vs[nxt][0][rs * 32 + scc]) = pv0;
      *(u16x8*)(&Vs[nxt][1][rs * 32 + scc]) = pv1;
      __syncthreads();
      cur = nxt;
    }
  }
#pragma unroll
  for (int r = 0; r < 4; ++r) {
    float inv = 1.0f / o4[r];     // l (all cols of ones-acc equal)
    int qr = qrow_base + r;
#pragma unroll
    for (int j = 0; j < 4; ++j)
      y[((rowb + qr) << 10) + hd * 64 + j * 16 + lq] = f2b(o[j][r] * inv);
  }
}

// --- 7) out[b,t,i*64+d] = sum_j y[b,t,j*64+d] * proj_tmp[i*16+j]  (FP32 out) ---
__global__ __launch_bounds__(256) void k_proj(const unsigned short* __restrict__ yb,
                                              const float* __restrict__ pt,
                                              float* __restrict__ out) {
  __shared__ float s_pt[256];
  s_pt[threadIdx.x] = pt[threadIdx.x];
  __syncthreads();
  int g = blockIdx.x * 256 + threadIdx.x;
  int bt = g >> 6, d = g & 63;
  float yj[16];
#pragma unroll
  for (int j = 0; j < 16; ++j) yj[j] = b2f(yb[(size_t)bt * 1024 + j * 64 + d]);
#pragma unroll
  for (int i = 0; i < 16; ++i) {
    float s = 0.f;
#pragma unroll
    for (int j = 0; j < 16; ++j) s += yj[j] * s_pt[i * 16 + j];
    out[(size_t)bt * 1024 + i * 64 + d] = s;
  }
}

extern "C" void kernel_launch(void* const* d_in, const int* in_sizes, int n_in,
                              void* d_out, int out_size, void* d_ws, size_t ws_size,
                              hipStream_t stream) {
  const float* x  = (const float*)d_in[0];   // [2][2048][1024] fp32
  const float* W  = (const float*)d_in[1];   // [1024][2048] fp32
  const float* vt = (const float*)d_in[2];   // [16][16] fp32
  const float* pt = (const float*)d_in[3];   // [16][16] fp32
  float* out = (float*)d_out;                // fp32 out

  char* ws = (char*)d_ws;
  unsigned short* xb  = (unsigned short*)(ws);                 //  8 MiB, reused as y
  unsigned short* Wt  = (unsigned short*)(ws + (8u  << 20));   //  4 MiB
  unsigned short* qkb = (unsigned short*)(ws + (12u << 20));   // 16 MiB
  unsigned short* vb  = (unsigned short*)(ws + (28u << 20));   //  8 MiB
  unsigned short* Vtr = (unsigned short*)(ws + (36u << 20));   //  8 MiB
  unsigned short* yb  = xb;  // xb dead after GEMM; flash writes y there

  k_cvt_x  <<<4096, 256, 0, stream>>>(x, xb, 4194304 / 4);
  k_trans_w<<<dim3(32, 16), 256, 0, stream>>>(W, Wt);
  k_gemm_qk<<<dim3(32, 16), 256, 0, stream>>>(xb, Wt, qkb);
  k_vcomp  <<<1024, 256, 0, stream>>>(x, vt, vb);
  k_vtrans <<<dim3(32, 16, 2), 256, 0, stream>>>(vb, Vtr);
  k_flash  <<<dim3(32, 16, 2), 256, 0, stream>>>(qkb, Vtr, yb);
  k_proj   <<<1024, 256, 0, stream>>>(yb, pt, out);
}